// Round 6
// baseline (391.493 us; speedup 1.0000x reference)
//
#include <hip/hip_runtime.h>
#include <hip/hip_bf16.h>

// GQA fwd: B=2, S=2048, D_IN=2048, H=16, KV=4, Dh=128, GROUP=4, scale=1/16.
// Inputs fp32, output fp32. Intermediates bf16.
// cvt(x)+tcvt(W) -> fused QKV 128^2-tile counted-vmcnt GEMM -> vectorized
// rmsrope(q,k) -> vtrans -> barrier-free MFMA flash attn (K/V read direct
// from L2, XCD-pinned kv-groups, uniform LPT, ctx in-place) -> 128^2 out GEMM.

using u16 = unsigned short;
using u32 = unsigned int;

constexpr int Ss  = 2048;
constexpr int Hh  = 16;
constexpr int KVH = 4;

typedef __attribute__((ext_vector_type(8))) short bf16x8;
typedef __attribute__((ext_vector_type(4))) float f32x4;

__device__ inline float b2f(u16 v)  { return __uint_as_float(((u32)v) << 16); }
__device__ inline u16 f2bf(float x) {
  u32 u = __float_as_uint(x);
  return (u16)((u + 0x7fffu + ((u >> 16) & 1u)) >> 16);
}
// packed RNE f32x2 -> bf16x2 (low half = first arg)
__device__ inline u32 cvtpk(float lo, float hi) {
  u32 r;
  asm("v_cvt_pk_bf16_f32 %0, %1, %2" : "=v"(r) : "v"(lo), "v"(hi));
  return r;
}

typedef const __attribute__((address_space(1))) unsigned int gas_u32;
typedef __attribute__((address_space(3))) unsigned int las_u32;
__device__ inline void gl16(const void* g, void* l) {
  __builtin_amdgcn_global_load_lds((gas_u32*)g, (las_u32*)l, 16, 0, 0);
}

// ---------------------------------------------------------------------------
__global__ __launch_bounds__(256) void cvt_bf16(const float* __restrict__ in,
                                                u16* __restrict__ out, int n4) {
  int i = blockIdx.x * 256 + threadIdx.x;
  if (i < n4) {
    float4 f = reinterpret_cast<const float4*>(in)[i];
    ushort4 o;
    o.x = f2bf(f.x); o.y = f2bf(f.y); o.z = f2bf(f.z); o.w = f2bf(f.w);
    reinterpret_cast<ushort4*>(out)[i] = o;
  }
}

// ---------------------------------------------------------------------------
// W [K][N] fp32 -> W^T [N][K] bf16, 64x64 LDS tiles; paired u32 out stores.
// ---------------------------------------------------------------------------
__global__ __launch_bounds__(256) void tcvt(const float* __restrict__ in,
                                            u16* __restrict__ out, int N, int K) {
  __shared__ u16 T[64][66];
  const int k0 = blockIdx.x * 64, n0 = blockIdx.y * 64;
  const int c = threadIdx.x & 63, rb = threadIdx.x >> 6;
#pragma unroll
  for (int p = 0; p < 16; p++) {
    int r = p * 4 + rb;
    T[c][r] = f2bf(in[(size_t)(k0 + r) * N + n0 + c]);
  }
  __syncthreads();
  const int c2 = threadIdx.x & 31, rb2 = threadIdx.x >> 5;
#pragma unroll
  for (int p = 0; p < 8; p++) {
    int nr = p * 8 + rb2;
    u32 v = *reinterpret_cast<const u32*>(&T[nr][c2 * 2]);
    *reinterpret_cast<u32*>(out + (size_t)(n0 + nr) * K + k0 + c2 * 2) = v;
  }
}

// ---------------------------------------------------------------------------
// v half of kv [4096 tok][1024] bf16 -> vT [(b*4+kvh)][128 d][2048 s]
// paired u32 out stores.
// ---------------------------------------------------------------------------
__global__ __launch_bounds__(256) void vtrans(const u16* __restrict__ kv,
                                              u16* __restrict__ vT) {
  __shared__ u16 T[64][66];
  const int s0 = blockIdx.x * 64, d0 = blockIdx.y * 64, z = blockIdx.z;
  const int b = z >> 2, kvh = z & 3;
  const int c = threadIdx.x & 63, rb = threadIdx.x >> 6;
#pragma unroll
  for (int p = 0; p < 16; p++) {
    int r = p * 4 + rb;
    T[c][r] = kv[(size_t)(b * Ss + s0 + r) * 1024 + 512 + kvh * 128 + d0 + c];
  }
  __syncthreads();
  const int c2 = threadIdx.x & 31, rb2 = threadIdx.x >> 5;
#pragma unroll
  for (int p = 0; p < 8; p++) {
    int dr = p * 8 + rb2;
    u32 v = *reinterpret_cast<const u32*>(&T[dr][c2 * 2]);
    *reinterpret_cast<u32*>(vT + ((size_t)z * 128 + d0 + dr) * Ss + s0 + c2 * 2) = v;
  }
}

// ---------------------------------------------------------------------------
// 128x128-tile GEMM, BK=64, 256 threads (4 waves 2Mx2N, per-wave 64x64).
// C[M x N] = A[M x K](bf16) @ Bt[N x K](bf16)^T.
// Counted-vmcnt double-buffer (stage 2 K-tiles ahead, vmcnt(8)); 64KB LDS ->
// 2 blocks/CU. Both-sides XOR chunk swizzle (row&7).
// MODE 0: split bf16 output: cols<2048 -> C0 stride 2048 (q), cols>=2048 ->
//         C1 stride 1024 (kv). MODE 1: f32 output C0 stride 2048.
// ---------------------------------------------------------------------------
template <int MODE>
__global__ __launch_bounds__(256, 2) void gemm128(const u16* __restrict__ A,
                                                  const u16* __restrict__ Bt,
                                                  void* __restrict__ C0,
                                                  u16* __restrict__ C1,
                                                  int K) {
  __shared__ u16 As[2][128 * 64];
  __shared__ u16 Bs[2][128 * 64];
  const int t = threadIdx.x;
  const int wid = t >> 6, lane = t & 63;
  const int lrow = lane & 15, quad = lane >> 4;
  const int wm = wid >> 1, wn = wid & 1;  // 2x2 wave grid; per-wave 64 x 64
  const int m0 = blockIdx.x * 128, n0 = blockIdx.y * 128;
  const int sw8 = (lrow & 7) << 3;

  const int srow = t >> 3;                      // 0..31 (+p*32)
  const int sco  = ((t & 7) ^ (srow & 7)) * 8;  // swizzled src col (u16)

  f32x4 acc[4][4];
#pragma unroll
  for (int i = 0; i < 4; i++)
#pragma unroll
    for (int j = 0; j < 4; j++) acc[i][j] = (f32x4)0.f;

#define STAGE(buf, k0)                                                     \
  {                                                                        \
    _Pragma("unroll") for (int p = 0; p < 4; p++) {                        \
      gl16(A + (size_t)(m0 + p * 32 + srow) * K + (k0) + sco,              \
           (char*)As[buf] + (p * 256 + t) * 16);                           \
      gl16(Bt + (size_t)(n0 + p * 32 + srow) * K + (k0) + sco,             \
           (char*)Bs[buf] + (p * 256 + t) * 16);                           \
    }                                                                      \
  }

  const int nk = K >> 6;  // 32
  STAGE(0, 0)
  STAGE(1, 64)
  asm volatile("s_waitcnt vmcnt(8)" ::: "memory");  // buf0 complete
  __builtin_amdgcn_s_barrier();
  __builtin_amdgcn_sched_barrier(0);

  for (int kt = 0; kt < nk; ++kt) {
    const int buf = kt & 1;
#pragma unroll
    for (int kc = 0; kc < 2; kc++) {
      bf16x8 af[4], bfr[4];
#pragma unroll
      for (int i = 0; i < 4; i++)
        af[i] = *reinterpret_cast<const bf16x8*>(
            &As[buf][(wm * 64 + i * 16 + lrow) * 64 + (((kc * 4 + quad) << 3) ^ sw8)]);
#pragma unroll
      for (int j = 0; j < 4; j++)
        bfr[j] = *reinterpret_cast<const bf16x8*>(
            &Bs[buf][(wn * 64 + j * 16 + lrow) * 64 + (((kc * 4 + quad) << 3) ^ sw8)]);
      __builtin_amdgcn_s_setprio(1);
#pragma unroll
      for (int i = 0; i < 4; i++)
#pragma unroll
        for (int j = 0; j < 4; j++)
          acc[i][j] =
              __builtin_amdgcn_mfma_f32_16x16x32_bf16(af[i], bfr[j], acc[i][j], 0, 0, 0);
      __builtin_amdgcn_s_setprio(0);
    }
    __builtin_amdgcn_sched_barrier(0);
    __builtin_amdgcn_s_barrier();  // all waves done reading buf
    __builtin_amdgcn_sched_barrier(0);
    if (kt + 2 < nk) {
      STAGE(buf, (kt + 2) * 64)
    }
    if (kt + 1 < nk) {
      if (kt + 2 < nk) {
        asm volatile("s_waitcnt vmcnt(8)" ::: "memory");  // buf kt+1 ready
      } else {
        asm volatile("s_waitcnt vmcnt(0)" ::: "memory");
      }
      __builtin_amdgcn_s_barrier();
      __builtin_amdgcn_sched_barrier(0);
    }
  }
#undef STAGE

  // epilogue
  if (MODE == 0) {
    u16* C;
    int stride, coff;
    if (n0 < 2048) { C = (u16*)C0; stride = 2048; coff = n0; }
    else           { C = C1;       stride = 1024; coff = n0 - 2048; }
#pragma unroll
    for (int i = 0; i < 4; i++)
#pragma unroll
      for (int j = 0; j < 4; j++)
#pragma unroll
        for (int r = 0; r < 4; r++) {
          int row = m0 + wm * 64 + i * 16 + quad * 4 + r;
          int col = coff + wn * 64 + j * 16 + lrow;
          C[(size_t)row * stride + col] = f2bf(acc[i][j][r]);
        }
  } else {
    float* C = (float*)C0;
#pragma unroll
    for (int i = 0; i < 4; i++)
#pragma unroll
      for (int j = 0; j < 4; j++)
#pragma unroll
        for (int r = 0; r < 4; r++) {
          int row = m0 + wm * 64 + i * 16 + quad * 4 + r;
          int col = n0 + wn * 64 + j * 16 + lrow;
          C[(size_t)row * 2048 + col] = acc[i][j][r];
        }
  }
}

// ---------------------------------------------------------------------------
// Fused RMSNorm + RoPE, vectorized: one wave per 128-el vector, lane l holds
// els (2l, 2l+1) as one u32; RoPE partner via one shfl_xor(32).
// ---------------------------------------------------------------------------
__global__ __launch_bounds__(256) void rmsrope2(u16* __restrict__ qbuf,
                                                u16* __restrict__ kvb,
                                                const float* __restrict__ qsc,
                                                const float* __restrict__ ksc,
                                                const float* __restrict__ cosb,
                                                const float* __restrict__ sinb) {
  const int w = threadIdx.x >> 6, lane = threadIdx.x & 63;
  const int vi = blockIdx.x * 4 + w;
  const int tok = vi / 20, j = vi - tok * 20;
  const int s = tok & (Ss - 1);
  const bool isq = j < 16;
  u16* p = isq ? (qbuf + (size_t)tok * 2048 + j * 128)
               : (kvb + (size_t)tok * 1024 + (j - 16) * 128);
  const float* scale = isq ? qsc : ksc;
  const float mult = isq ? 0.0625f : 1.0f;

  u32* p32 = reinterpret_cast<u32*>(p);
  u32 v = p32[lane];
  float e0 = b2f((u16)(v & 0xffff)), e1 = b2f((u16)(v >> 16));
  float ss = e0 * e0 + e1 * e1;
#pragma unroll
  for (int off = 32; off > 0; off >>= 1) ss += __shfl_xor(ss, off);
  float rr = rsqrtf(ss * (1.0f / 128.0f) + 1e-6f);
  float2 sc = reinterpret_cast<const float2*>(scale)[lane];
  float x0 = e0 * rr * sc.x;
  float x1 = e1 * rr * sc.y;
  float px0 = __shfl_xor(x0, 32);
  float px1 = __shfl_xor(x1, 32);
  float2 c  = reinterpret_cast<const float2*>(cosb + s * 128)[lane];
  float2 sn = reinterpret_cast<const float2*>(sinb + s * 128)[lane];
  float sgn = (lane < 32) ? -1.0f : 1.0f;
  float o0 = (x0 * c.x + sgn * px0 * sn.x) * mult;
  float o1 = (x1 * c.y + sgn * px1 * sn.y) * mult;
  p32[lane] = cvtpk(o0, o1);
}

// ---------------------------------------------------------------------------
// MFMA flash attention (causal, GQA) -- BARRIER-FREE. 64-row q-tiles, 2 waves
// x 32 q-rows, 1024 blocks x 128 threads (exactly 4/CU, all co-resident).
// K and V fragments are read DIRECTLY from global (kvb / vTb): both are 16B
// contiguous per lane in the existing layouts, and the per-(b,kvh) working
// set is 1MB -- L2-resident (Common-mistake #7 / m169: don't stage what
// caches). No K/V LDS, no gl16, no __syncthreads; LDS only holds the 5KB
// per-wave P-transpose buffer. Waves run fully independently.
// blockIdx = s*8 + g pins kv-group g=(b,kvh) to one XCD (blk%8): each XCD L2
// holds exactly its 1MB group. Within a group s=(r=head,pos), qt = pos or
// 31-pos alternating per r -> per-CU tile count uniform (66).
// Lane-local softmax + defer-max (T13) + cvt_pk pack + transposed PV.
// ctx written IN-PLACE into qbuf (block-exclusive rows).
// ---------------------------------------------------------------------------
__global__ __launch_bounds__(128, 2) void attn_mfma(const u16* __restrict__ qb,
                                                    const u16* __restrict__ kv,
                                                    const u16* __restrict__ vT,
                                                    u16* __restrict__ ctx) {
  __shared__ u16 Ps[2][32 * 40]; // per-wave P chunk [q][key] stride 40
  const int i = blockIdx.x;
  const int g8 = i & 7, s = i >> 3;
  const int r = s >> 5, pos = s & 31;
  const int qtile = (r & 1) ? pos : 31 - pos;
  const int kvh = g8 & 3, b = g8 >> 2;
  const int h = kvh * 4 + r;
  const int t = threadIdx.x, w = t >> 6, lane = t & 63;
  const int lrow = lane & 15, quad = lane >> 4;
  const int qw = qtile * 64 + w * 32;  // wave's first q row

  const u16* kbase = kv + (size_t)b * Ss * 1024 + kvh * 128;   // key stride 1024
  const u16* vbase = vT + (size_t)(b * KVH + kvh) * 128 * Ss;  // + d*Ss + s

  // stationary Q B-frags: qf[g][c] -> Q[qw+g*16+lrow][c*32+quad*8 ..+7]
  bf16x8 qf[2][4];
#pragma unroll
  for (int g = 0; g < 2; g++)
#pragma unroll
    for (int c = 0; c < 4; c++)
      qf[g][c] = *reinterpret_cast<const bf16x8*>(
          qb + ((size_t)(b * Ss + qw + g * 16 + lrow) * Hh + h) * 128 + c * 32 + quad * 8);

  f32x4 o[2][8];  // o[g][n]: d = n*16+quad*4+r, q = qw+g*16+lrow
#pragma unroll
  for (int g = 0; g < 2; g++)
#pragma unroll
    for (int n = 0; n < 8; n++) o[g][n] = (f32x4)0.f;
  float mx[2] = {-1e30f, -1e30f}, ls[2] = {0.f, 0.f};

  const int ntile = qtile + 1;
  for (int kt = 0; kt < ntile; kt++) {
    const int kb0 = kt * 64;

    // S^T[key][q]: st[g][mt], key = kb0+mt*16+quad*4+rr, q = qw+g*16+lrow.
    // K fragments straight from global: row kb0+mt*16+lrow, 16B at d-offset.
    f32x4 st[2][4];
#pragma unroll
    for (int g = 0; g < 2; g++)
#pragma unroll
      for (int mt = 0; mt < 4; mt++) st[g][mt] = (f32x4)0.f;
#pragma unroll
    for (int c = 0; c < 4; c++) {
      bf16x8 kf[4];
#pragma unroll
      for (int mt = 0; mt < 4; mt++)
        kf[mt] = *reinterpret_cast<const bf16x8*>(
            kbase + (size_t)(kb0 + mt * 16 + lrow) * 1024 + c * 32 + quad * 8);
      __builtin_amdgcn_s_setprio(1);
#pragma unroll
      for (int mt = 0; mt < 4; mt++)
#pragma unroll
        for (int g = 0; g < 2; g++)
          st[g][mt] =
              __builtin_amdgcn_mfma_f32_16x16x32_bf16(kf[mt], qf[g][c], st[g][mt], 0, 0, 0);
      __builtin_amdgcn_s_setprio(0);
    }
    // causal mask (only the diagonal tile)
    if (kb0 + 63 > qw) {
#pragma unroll
      for (int g = 0; g < 2; g++) {
        int qg = qw + g * 16 + lrow;
#pragma unroll
        for (int mt = 0; mt < 4; mt++) {
          int kg = kb0 + mt * 16 + quad * 4;
#pragma unroll
          for (int rr = 0; rr < 4; rr++)
            st[g][mt][rr] = (kg + rr > qg) ? -1e30f : st[g][mt][rr];
        }
      }
    }
    // online softmax, lane-local state (q = lrow, replicated over quads)
    float tmv[2];
#pragma unroll
    for (int g = 0; g < 2; g++) {
      f32x4 m4;
#pragma unroll
      for (int rr = 0; rr < 4; rr++)
        m4[rr] = fmaxf(fmaxf(st[g][0][rr], st[g][1][rr]), fmaxf(st[g][2][rr], st[g][3][rr]));
      float tm = fmaxf(fmaxf(m4[0], m4[1]), fmaxf(m4[2], m4[3]));
      tm = fmaxf(tm, __shfl_xor(tm, 16));
      tm = fmaxf(tm, __shfl_xor(tm, 32));
      tmv[g] = tm;
    }
    // defer-max (T13): rescale only if some row grew its max by >8.
    if (__any((tmv[0] > mx[0] + 8.0f) || (tmv[1] > mx[1] + 8.0f))) {
#pragma unroll
      for (int g = 0; g < 2; g++) {
        float mn = fmaxf(mx[g], tmv[g]);
        float a = __expf(mx[g] - mn);
        mx[g] = mn;
        ls[g] *= a;
#pragma unroll
        for (int n = 0; n < 8; n++) o[g][n] *= a;
      }
    }
#pragma unroll
    for (int g = 0; g < 2; g++) {
      float tsum = 0.f;
#pragma unroll
      for (int mt = 0; mt < 4; mt++)
#pragma unroll
        for (int rr = 0; rr < 4; rr++) {
          float pv = __expf(st[g][mt][rr] - mx[g]);
          st[g][mt][rr] = pv;
          tsum += pv;
        }
      tsum += __shfl_xor(tsum, 16);
      tsum += __shfl_xor(tsum, 32);
      ls[g] += tsum;
    }
    // PV in 2 key-chunks of 32: pack P (cvt_pk) -> per-wave LDS -> B-frag
    // P^T[k][q]; V fragments straight from global (vT row = d, s-contig 16B).
#pragma unroll
    for (int c2 = 0; c2 < 2; c2++) {
#pragma unroll
      for (int g = 0; g < 2; g++)
#pragma unroll
        for (int mh = 0; mh < 2; mh++) {
          const f32x4 sv = st[g][c2 * 2 + mh];
          uint2 pk;
          pk.x = cvtpk(sv[0], sv[1]);
          pk.y = cvtpk(sv[2], sv[3]);
          *reinterpret_cast<uint2*>(
              &Ps[w][(g * 16 + lrow) * 40 + mh * 16 + quad * 4]) = pk;
        }
      bf16x8 pfr[2];
#pragma unroll
      for (int g = 0; g < 2; g++)
        pfr[g] = *reinterpret_cast<const bf16x8*>(
            &Ps[w][(g * 16 + lrow) * 40 + quad * 8]);
#pragma unroll
      for (int half = 0; half < 2; half++) {
        bf16x8 vf[4];
#pragma unroll
        for (int n4 = 0; n4 < 4; n4++) {
          int n = half * 4 + n4;
          vf[n4] = *reinterpret_cast<const bf16x8*>(
              vbase + (size_t)(n * 16 + lrow) * Ss + kb0 + c2 * 32 + quad * 8);
        }
        __builtin_amdgcn_s_setprio(1);
#pragma unroll
        for (int n4 = 0; n4 < 4; n4++)
#pragma unroll
          for (int g = 0; g < 2; g++)
            o[g][half * 4 + n4] = __builtin_amdgcn_mfma_f32_16x16x32_bf16(
                vf[n4], pfr[g], o[g][half * 4 + n4], 0, 0, 0);
        __builtin_amdgcn_s_setprio(0);
      }
    }
  }

  // epilogue: divide by l (lane-local), packed bf16 store
#pragma unroll
  for (int g = 0; g < 2; g++) {
    float linv = 1.0f / ls[g];
    u16* obase = ctx + ((size_t)(b * Ss + qw + g * 16 + lrow) * Hh + h) * 128 + quad * 4;
#pragma unroll
    for (int n = 0; n < 8; n++) {
      uint2 pk;
      pk.x = cvtpk(o[g][n][0] * linv, o[g][n][1] * linv);
      pk.y = cvtpk(o[g][n][2] * linv, o[g][n][3] * linv);
      *reinterpret_cast<uint2*>(obase + n * 16) = pk;
    }
  }
}

// ---------------------------------------------------------------------------
extern "C" void kernel_launch(void* const* d_in, const int* in_sizes, int n_in,
                              void* d_out, int out_size, void* d_ws, size_t ws_size,
                              hipStream_t stream) {
  const float* x    = (const float*)d_in[0];
  // d_in[1] = mask (unused; causal handled analytically)
  const float* cosb = (const float*)d_in[2];
  const float* sinb = (const float*)d_in[3];
  const float* Wq   = (const float*)d_in[4];
  const float* Wk   = (const float*)d_in[5];
  const float* Wv   = (const float*)d_in[6];
  const float* Wo   = (const float*)d_in[7];
  const float* qsc  = (const float*)d_in[8];
  const float* ksc  = (const float*)d_in[9];

  const int M = 2 * Ss;  // 4096 tokens
  // workspace (u16 elems):
  // xb    [0        .. 8388608)   x bf16 [4096][2048]; dead after QKV gemm
  // Wqkv  [8388608  .. 14680064)  W^T [3072][2048]; dead after QKV gemm
  // qbuf  [14680064 .. 23068672)  q [tok][16][128]; ctx written in-place
  // kvb   [23068672 .. 27262976)  k|v [tok][1024]
  // vTb   = alias of xb[0..2097152)   (used from vtrans onward)
  // WoT   = alias of Wqkv[0..4194304) (used from tcvt(Wo) onward)
  u16* xb   = (u16*)d_ws;
  u16* Wqkv = xb + (size_t)8388608;
  u16* qbuf = Wqkv + (size_t)6291456;
  u16* kvb  = qbuf + (size_t)8388608;
  u16* vTb  = xb;
  u16* WoT  = Wqkv;

  cvt_bf16<<<8192, 256, 0, stream>>>(x, xb, 2097152);

  tcvt<<<dim3(32, 32), 256, 0, stream>>>(Wq, Wqkv, 2048, 2048);
  tcvt<<<dim3(32, 8), 256, 0, stream>>>(Wk, Wqkv + (size_t)2048 * 2048, 512, 2048);
  tcvt<<<dim3(32, 8), 256, 0, stream>>>(Wv, Wqkv + (size_t)2560 * 2048, 512, 2048);

  // fused QKV projection: [4096][3072] split into qbuf (cols<2048) / kvb
  gemm128<0><<<dim3(32, 24), 256, 0, stream>>>(xb, Wqkv, qbuf, kvb, 2048);

  rmsrope2<<<(M * 20) / 4, 256, 0, stream>>>(qbuf, kvb, qsc, ksc, cosb, sinb);

  vtrans<<<dim3(32, 2, 8), 256, 0, stream>>>(kvb, vTb);

  attn_mfma<<<dim3(1024), 128, 0, stream>>>(qbuf, kvb, vTb, qbuf /*in-place*/);

  tcvt<<<dim3(32, 32), 256, 0, stream>>>(Wo, WoT, 2048, 2048);
  gemm128<1><<<dim3(32, 16), 256, 0, stream>>>(qbuf, WoT, d_out, nullptr, 2048);
}

// Round 7
// 350.253 us; speedup vs baseline: 1.1177x; 1.1177x over previous
//
#include <hip/hip_runtime.h>
#include <hip/hip_bf16.h>

// GQA fwd: B=2, S=2048, D_IN=2048, H=16, KV=4, Dh=128, GROUP=4, scale=1/16.
// Inputs fp32, output fp32. Intermediates bf16.
// cvt(x)+tcvt(W) -> fused QKV 128^2-tile counted-vmcnt GEMM -> vectorized
// rmsrope(q,k) -> vtrans -> MFMA flash attn (K LDS-staged, V direct-from-L2
// with post-QK prefetch, XCD-pinned kv-groups, ctx in-place) -> 128^2 out GEMM.

using u16 = unsigned short;
using u32 = unsigned int;

constexpr int Ss  = 2048;
constexpr int Hh  = 16;
constexpr int KVH = 4;

typedef __attribute__((ext_vector_type(8))) short bf16x8;
typedef __attribute__((ext_vector_type(4))) float f32x4;

__device__ inline float b2f(u16 v)  { return __uint_as_float(((u32)v) << 16); }
__device__ inline u16 f2bf(float x) {
  u32 u = __float_as_uint(x);
  return (u16)((u + 0x7fffu + ((u >> 16) & 1u)) >> 16);
}
// packed RNE f32x2 -> bf16x2 (low half = first arg)
__device__ inline u32 cvtpk(float lo, float hi) {
  u32 r;
  asm("v_cvt_pk_bf16_f32 %0, %1, %2" : "=v"(r) : "v"(lo), "v"(hi));
  return r;
}

typedef const __attribute__((address_space(1))) unsigned int gas_u32;
typedef __attribute__((address_space(3))) unsigned int las_u32;
__device__ inline void gl16(const void* g, void* l) {
  __builtin_amdgcn_global_load_lds((gas_u32*)g, (las_u32*)l, 16, 0, 0);
}

// ---------------------------------------------------------------------------
__global__ __launch_bounds__(256) void cvt_bf16(const float* __restrict__ in,
                                                u16* __restrict__ out, int n4) {
  int i = blockIdx.x * 256 + threadIdx.x;
  if (i < n4) {
    float4 f = reinterpret_cast<const float4*>(in)[i];
    ushort4 o;
    o.x = f2bf(f.x); o.y = f2bf(f.y); o.z = f2bf(f.z); o.w = f2bf(f.w);
    reinterpret_cast<ushort4*>(out)[i] = o;
  }
}

// ---------------------------------------------------------------------------
// W [K][N] fp32 -> W^T [N][K] bf16, 64x64 LDS tiles; paired u32 out stores.
// ---------------------------------------------------------------------------
__global__ __launch_bounds__(256) void tcvt(const float* __restrict__ in,
                                            u16* __restrict__ out, int N, int K) {
  __shared__ u16 T[64][66];
  const int k0 = blockIdx.x * 64, n0 = blockIdx.y * 64;
  const int c = threadIdx.x & 63, rb = threadIdx.x >> 6;
#pragma unroll
  for (int p = 0; p < 16; p++) {
    int r = p * 4 + rb;
    T[c][r] = f2bf(in[(size_t)(k0 + r) * N + n0 + c]);
  }
  __syncthreads();
  const int c2 = threadIdx.x & 31, rb2 = threadIdx.x >> 5;
#pragma unroll
  for (int p = 0; p < 8; p++) {
    int nr = p * 8 + rb2;
    u32 v = *reinterpret_cast<const u32*>(&T[nr][c2 * 2]);
    *reinterpret_cast<u32*>(out + (size_t)(n0 + nr) * K + k0 + c2 * 2) = v;
  }
}

// ---------------------------------------------------------------------------
// v half of kv [4096 tok][1024] bf16 -> vT [(b*4+kvh)][128 d][2048 s]
// paired u32 out stores.
// ---------------------------------------------------------------------------
__global__ __launch_bounds__(256) void vtrans(const u16* __restrict__ kv,
                                              u16* __restrict__ vT) {
  __shared__ u16 T[64][66];
  const int s0 = blockIdx.x * 64, d0 = blockIdx.y * 64, z = blockIdx.z;
  const int b = z >> 2, kvh = z & 3;
  const int c = threadIdx.x & 63, rb = threadIdx.x >> 6;
#pragma unroll
  for (int p = 0; p < 16; p++) {
    int r = p * 4 + rb;
    T[c][r] = kv[(size_t)(b * Ss + s0 + r) * 1024 + 512 + kvh * 128 + d0 + c];
  }
  __syncthreads();
  const int c2 = threadIdx.x & 31, rb2 = threadIdx.x >> 5;
#pragma unroll
  for (int p = 0; p < 8; p++) {
    int dr = p * 8 + rb2;
    u32 v = *reinterpret_cast<const u32*>(&T[dr][c2 * 2]);
    *reinterpret_cast<u32*>(vT + ((size_t)z * 128 + d0 + dr) * Ss + s0 + c2 * 2) = v;
  }
}

// ---------------------------------------------------------------------------
// 128x128-tile GEMM, BK=64, 256 threads (4 waves 2Mx2N, per-wave 64x64).
// C[M x N] = A[M x K](bf16) @ Bt[N x K](bf16)^T.
// Counted-vmcnt double-buffer (stage 2 K-tiles ahead, vmcnt(8)); 64KB LDS ->
// 2 blocks/CU. Both-sides XOR chunk swizzle (row&7).
// MODE 0: split bf16 output: cols<2048 -> C0 stride 2048 (q), cols>=2048 ->
//         C1 stride 1024 (kv). MODE 1: f32 output C0 stride 2048.
// ---------------------------------------------------------------------------
template <int MODE>
__global__ __launch_bounds__(256, 2) void gemm128(const u16* __restrict__ A,
                                                  const u16* __restrict__ Bt,
                                                  void* __restrict__ C0,
                                                  u16* __restrict__ C1,
                                                  int K) {
  __shared__ u16 As[2][128 * 64];
  __shared__ u16 Bs[2][128 * 64];
  const int t = threadIdx.x;
  const int wid = t >> 6, lane = t & 63;
  const int lrow = lane & 15, quad = lane >> 4;
  const int wm = wid >> 1, wn = wid & 1;  // 2x2 wave grid; per-wave 64 x 64
  const int m0 = blockIdx.x * 128, n0 = blockIdx.y * 128;
  const int sw8 = (lrow & 7) << 3;

  const int srow = t >> 3;                      // 0..31 (+p*32)
  const int sco  = ((t & 7) ^ (srow & 7)) * 8;  // swizzled src col (u16)

  f32x4 acc[4][4];
#pragma unroll
  for (int i = 0; i < 4; i++)
#pragma unroll
    for (int j = 0; j < 4; j++) acc[i][j] = (f32x4)0.f;

#define STAGE(buf, k0)                                                     \
  {                                                                        \
    _Pragma("unroll") for (int p = 0; p < 4; p++) {                        \
      gl16(A + (size_t)(m0 + p * 32 + srow) * K + (k0) + sco,              \
           (char*)As[buf] + (p * 256 + t) * 16);                           \
      gl16(Bt + (size_t)(n0 + p * 32 + srow) * K + (k0) + sco,             \
           (char*)Bs[buf] + (p * 256 + t) * 16);                           \
    }                                                                      \
  }

  const int nk = K >> 6;  // 32
  STAGE(0, 0)
  STAGE(1, 64)
  asm volatile("s_waitcnt vmcnt(8)" ::: "memory");  // buf0 complete
  __builtin_amdgcn_s_barrier();
  __builtin_amdgcn_sched_barrier(0);

  for (int kt = 0; kt < nk; ++kt) {
    const int buf = kt & 1;
#pragma unroll
    for (int kc = 0; kc < 2; kc++) {
      bf16x8 af[4], bfr[4];
#pragma unroll
      for (int i = 0; i < 4; i++)
        af[i] = *reinterpret_cast<const bf16x8*>(
            &As[buf][(wm * 64 + i * 16 + lrow) * 64 + (((kc * 4 + quad) << 3) ^ sw8)]);
#pragma unroll
      for (int j = 0; j < 4; j++)
        bfr[j] = *reinterpret_cast<const bf16x8*>(
            &Bs[buf][(wn * 64 + j * 16 + lrow) * 64 + (((kc * 4 + quad) << 3) ^ sw8)]);
      __builtin_amdgcn_s_setprio(1);
#pragma unroll
      for (int i = 0; i < 4; i++)
#pragma unroll
        for (int j = 0; j < 4; j++)
          acc[i][j] =
              __builtin_amdgcn_mfma_f32_16x16x32_bf16(af[i], bfr[j], acc[i][j], 0, 0, 0);
      __builtin_amdgcn_s_setprio(0);
    }
    __builtin_amdgcn_sched_barrier(0);
    __builtin_amdgcn_s_barrier();  // all waves done reading buf
    __builtin_amdgcn_sched_barrier(0);
    if (kt + 2 < nk) {
      STAGE(buf, (kt + 2) * 64)
    }
    if (kt + 1 < nk) {
      if (kt + 2 < nk) {
        asm volatile("s_waitcnt vmcnt(8)" ::: "memory");  // buf kt+1 ready
      } else {
        asm volatile("s_waitcnt vmcnt(0)" ::: "memory");
      }
      __builtin_amdgcn_s_barrier();
      __builtin_amdgcn_sched_barrier(0);
    }
  }
#undef STAGE

  // epilogue
  if (MODE == 0) {
    u16* C;
    int stride, coff;
    if (n0 < 2048) { C = (u16*)C0; stride = 2048; coff = n0; }
    else           { C = C1;       stride = 1024; coff = n0 - 2048; }
#pragma unroll
    for (int i = 0; i < 4; i++)
#pragma unroll
      for (int j = 0; j < 4; j++)
#pragma unroll
        for (int r = 0; r < 4; r++) {
          int row = m0 + wm * 64 + i * 16 + quad * 4 + r;
          int col = coff + wn * 64 + j * 16 + lrow;
          C[(size_t)row * stride + col] = f2bf(acc[i][j][r]);
        }
  } else {
    float* C = (float*)C0;
#pragma unroll
    for (int i = 0; i < 4; i++)
#pragma unroll
      for (int j = 0; j < 4; j++)
#pragma unroll
        for (int r = 0; r < 4; r++) {
          int row = m0 + wm * 64 + i * 16 + quad * 4 + r;
          int col = n0 + wn * 64 + j * 16 + lrow;
          C[(size_t)row * 2048 + col] = acc[i][j][r];
        }
  }
}

// ---------------------------------------------------------------------------
// Fused RMSNorm + RoPE, vectorized: one wave per 128-el vector, lane l holds
// els (2l, 2l+1) as one u32; RoPE partner via one shfl_xor(32).
// ---------------------------------------------------------------------------
__global__ __launch_bounds__(256) void rmsrope2(u16* __restrict__ qbuf,
                                                u16* __restrict__ kvb,
                                                const float* __restrict__ qsc,
                                                const float* __restrict__ ksc,
                                                const float* __restrict__ cosb,
                                                const float* __restrict__ sinb) {
  const int w = threadIdx.x >> 6, lane = threadIdx.x & 63;
  const int vi = blockIdx.x * 4 + w;
  const int tok = vi / 20, j = vi - tok * 20;
  const int s = tok & (Ss - 1);
  const bool isq = j < 16;
  u16* p = isq ? (qbuf + (size_t)tok * 2048 + j * 128)
               : (kvb + (size_t)tok * 1024 + (j - 16) * 128);
  const float* scale = isq ? qsc : ksc;
  const float mult = isq ? 0.0625f : 1.0f;

  u32* p32 = reinterpret_cast<u32*>(p);
  u32 v = p32[lane];
  float e0 = b2f((u16)(v & 0xffff)), e1 = b2f((u16)(v >> 16));
  float ss = e0 * e0 + e1 * e1;
#pragma unroll
  for (int off = 32; off > 0; off >>= 1) ss += __shfl_xor(ss, off);
  float rr = rsqrtf(ss * (1.0f / 128.0f) + 1e-6f);
  float2 sc = reinterpret_cast<const float2*>(scale)[lane];
  float x0 = e0 * rr * sc.x;
  float x1 = e1 * rr * sc.y;
  float px0 = __shfl_xor(x0, 32);
  float px1 = __shfl_xor(x1, 32);
  float2 c  = reinterpret_cast<const float2*>(cosb + s * 128)[lane];
  float2 sn = reinterpret_cast<const float2*>(sinb + s * 128)[lane];
  float sgn = (lane < 32) ? -1.0f : 1.0f;
  float o0 = (x0 * c.x + sgn * px0 * sn.x) * mult;
  float o1 = (x1 * c.y + sgn * px1 * sn.y) * mult;
  p32[lane] = cvtpk(o0, o1);
}

// ---------------------------------------------------------------------------
// MFMA flash attention (causal, GQA). 64-row q-tiles, 2 waves x 32 q-rows,
// 1024 blocks x 128 threads (4/CU). HYBRID staging (R6 post-mortem):
//  - K: LDS-staged via gl16 (8/thread), both-sides XOR swizzle, 2 barriers
//    per tile -- keeps the pipelining anchor R6 destroyed.
//  - V: read DIRECTLY from global vTb (16B/lane contiguous; per-(b,kvh)
//    working set 512KB = L2-resident, XCD-pinned). Loads issued right after
//    the QK MFMA phase so softmax+pack (~350cy) hides L2 latency; no Vs LDS
//    traffic (block-tile LDS ops drop ~45%).
// blockIdx = s*8 + g pins kv-group g=(b,kvh) to one XCD (blk%8). Within a
// group s=(r=head,pos), qt = pos or 31-pos alternating per r -> per-CU tile
// count uniform (66). Lane-local softmax + defer-max (T13) + cvt_pk pack +
// transposed PV. ctx written IN-PLACE into qbuf (block-exclusive rows).
// LDS: 16KB Ks + 5KB Ps = 21504 B.
// ---------------------------------------------------------------------------
__global__ __launch_bounds__(128, 2) void attn_mfma(const u16* __restrict__ qb,
                                                    const u16* __restrict__ kv,
                                                    const u16* __restrict__ vT,
                                                    u16* __restrict__ ctx) {
  __shared__ u16 Ks[64 * 128];   // [key][d] linear, chunk^=(key&7)
  __shared__ u16 Ps[2][32 * 40]; // per-wave P chunk [q][key] stride 40
  const int i = blockIdx.x;
  const int g8 = i & 7, s = i >> 3;
  const int r = s >> 5, pos = s & 31;
  const int qtile = (r & 1) ? pos : 31 - pos;
  const int kvh = g8 & 3, b = g8 >> 2;
  const int h = kvh * 4 + r;
  const int t = threadIdx.x, w = t >> 6, lane = t & 63;
  const int lrow = lane & 15, quad = lane >> 4;
  const int qw = qtile * 64 + w * 32;  // wave's first q row

  const u16* kbase = kv + (size_t)b * Ss * 1024 + kvh * 128;   // key stride 1024
  const u16* vbase = vT + (size_t)(b * KVH + kvh) * 128 * Ss;  // + d*Ss + s

  const int kr  = t >> 4;                       // K row 0..7 (+p8*8)
  const int kco = ((t & 15) ^ (kr & 7)) * 8;    // u16 offset within K row
  const int sw8 = (lrow & 7) << 3;              // read-side XOR (u16 units)

  // stationary Q B-frags: qf[g][c] -> Q[qw+g*16+lrow][c*32+quad*8 ..+7]
  bf16x8 qf[2][4];
#pragma unroll
  for (int g = 0; g < 2; g++)
#pragma unroll
    for (int c = 0; c < 4; c++)
      qf[g][c] = *reinterpret_cast<const bf16x8*>(
          qb + ((size_t)(b * Ss + qw + g * 16 + lrow) * Hh + h) * 128 + c * 32 + quad * 8);

  f32x4 o[2][8];  // o[g][n]: d = n*16+quad*4+rr, q = qw+g*16+lrow
#pragma unroll
  for (int g = 0; g < 2; g++)
#pragma unroll
    for (int n = 0; n < 8; n++) o[g][n] = (f32x4)0.f;
  float mx[2] = {-1e30f, -1e30f}, ls[2] = {0.f, 0.f};

  const int ntile = qtile + 1;
  for (int kt = 0; kt < ntile; kt++) {
    const int kb0 = kt * 64;
    __syncthreads();  // all waves done reading previous tile's Ks
#pragma unroll
    for (int p8 = 0; p8 < 8; p8++)
      gl16(kbase + (size_t)(kb0 + p8 * 8 + kr) * 1024 + kco,
           (char*)Ks + (p8 * 128 + t) * 16);
    __syncthreads();  // implicit vmcnt(0): Ks ready

    // S^T[key][q]: st[g][mt], key = kb0+mt*16+quad*4+rr, q = qw+g*16+lrow
    f32x4 st[2][4];
#pragma unroll
    for (int g = 0; g < 2; g++)
#pragma unroll
      for (int mt = 0; mt < 4; mt++) st[g][mt] = (f32x4)0.f;
#pragma unroll
    for (int c = 0; c < 4; c++) {
      bf16x8 kf[4];
#pragma unroll
      for (int mt = 0; mt < 4; mt++)
        kf[mt] = *reinterpret_cast<const bf16x8*>(
            &Ks[(mt * 16 + lrow) * 128 + ((((c * 4 + quad) << 3)) ^ sw8)]);
      __builtin_amdgcn_s_setprio(1);
#pragma unroll
      for (int mt = 0; mt < 4; mt++)
#pragma unroll
        for (int g = 0; g < 2; g++)
          st[g][mt] =
              __builtin_amdgcn_mfma_f32_16x16x32_bf16(kf[mt], qf[g][c], st[g][mt], 0, 0, 0);
      __builtin_amdgcn_s_setprio(0);
    }

    // V prefetch into regs (direct from global/L2, vT row = d, s-contig 16B);
    // issued here so the softmax below hides the load latency.
    bf16x8 vfa[2][8];
#pragma unroll
    for (int c2 = 0; c2 < 2; c2++)
#pragma unroll
      for (int n = 0; n < 8; n++)
        vfa[c2][n] = *reinterpret_cast<const bf16x8*>(
            vbase + (size_t)(n * 16 + lrow) * Ss + kb0 + c2 * 32 + quad * 8);

    // causal mask (only the diagonal tile)
    if (kb0 + 63 > qw) {
#pragma unroll
      for (int g = 0; g < 2; g++) {
        int qg = qw + g * 16 + lrow;
#pragma unroll
        for (int mt = 0; mt < 4; mt++) {
          int kg = kb0 + mt * 16 + quad * 4;
#pragma unroll
          for (int rr = 0; rr < 4; rr++)
            st[g][mt][rr] = (kg + rr > qg) ? -1e30f : st[g][mt][rr];
        }
      }
    }
    // online softmax, lane-local state (q = lrow, replicated over quads)
    float tmv[2];
#pragma unroll
    for (int g = 0; g < 2; g++) {
      f32x4 m4;
#pragma unroll
      for (int rr = 0; rr < 4; rr++)
        m4[rr] = fmaxf(fmaxf(st[g][0][rr], st[g][1][rr]), fmaxf(st[g][2][rr], st[g][3][rr]));
      float tm = fmaxf(fmaxf(m4[0], m4[1]), fmaxf(m4[2], m4[3]));
      tm = fmaxf(tm, __shfl_xor(tm, 16));
      tm = fmaxf(tm, __shfl_xor(tm, 32));
      tmv[g] = tm;
    }
    // defer-max (T13): rescale only if some row grew its max by >8.
    if (__any((tmv[0] > mx[0] + 8.0f) || (tmv[1] > mx[1] + 8.0f))) {
#pragma unroll
      for (int g = 0; g < 2; g++) {
        float mn = fmaxf(mx[g], tmv[g]);
        float a = __expf(mx[g] - mn);
        mx[g] = mn;
        ls[g] *= a;
#pragma unroll
        for (int n = 0; n < 8; n++) o[g][n] *= a;
      }
    }
#pragma unroll
    for (int g = 0; g < 2; g++) {
      float tsum = 0.f;
#pragma unroll
      for (int mt = 0; mt < 4; mt++)
#pragma unroll
        for (int rr = 0; rr < 4; rr++) {
          float pv = __expf(st[g][mt][rr] - mx[g]);
          st[g][mt][rr] = pv;
          tsum += pv;
        }
      tsum += __shfl_xor(tsum, 16);
      tsum += __shfl_xor(tsum, 32);
      ls[g] += tsum;
    }
    // PV in 2 key-chunks of 32: pack P (cvt_pk) -> per-wave LDS -> B-frag
    // P^T[k][q]; V from the prefetched registers.
#pragma unroll
    for (int c2 = 0; c2 < 2; c2++) {
#pragma unroll
      for (int g = 0; g < 2; g++)
#pragma unroll
        for (int mh = 0; mh < 2; mh++) {
          const f32x4 sv = st[g][c2 * 2 + mh];
          uint2 pk;
          pk.x = cvtpk(sv[0], sv[1]);
          pk.y = cvtpk(sv[2], sv[3]);
          *reinterpret_cast<uint2*>(
              &Ps[w][(g * 16 + lrow) * 40 + mh * 16 + quad * 4]) = pk;
        }
      bf16x8 pfr[2];
#pragma unroll
      for (int g = 0; g < 2; g++)
        pfr[g] = *reinterpret_cast<const bf16x8*>(
            &Ps[w][(g * 16 + lrow) * 40 + quad * 8]);
      __builtin_amdgcn_s_setprio(1);
#pragma unroll
      for (int n = 0; n < 8; n++)
#pragma unroll
        for (int g = 0; g < 2; g++)
          o[g][n] = __builtin_amdgcn_mfma_f32_16x16x32_bf16(vfa[c2][n], pfr[g], o[g][n], 0, 0, 0);
      __builtin_amdgcn_s_setprio(0);
    }
  }

  // epilogue: divide by l (lane-local), packed bf16 store
#pragma unroll
  for (int g = 0; g < 2; g++) {
    float linv = 1.0f / ls[g];
    u16* obase = ctx + ((size_t)(b * Ss + qw + g * 16 + lrow) * Hh + h) * 128 + quad * 4;
#pragma unroll
    for (int n = 0; n < 8; n++) {
      uint2 pk;
      pk.x = cvtpk(o[g][n][0] * linv, o[g][n][1] * linv);
      pk.y = cvtpk(o[g][n][2] * linv, o[g][n][3] * linv);
      *reinterpret_cast<uint2*>(obase + n * 16) = pk;
    }
  }
}

// ---------------------------------------------------------------------------
extern "C" void kernel_launch(void* const* d_in, const int* in_sizes, int n_in,
                              void* d_out, int out_size, void* d_ws, size_t ws_size,
                              hipStream_t stream) {
  const float* x    = (const float*)d_in[0];
  // d_in[1] = mask (unused; causal handled analytically)
  const float* cosb = (const float*)d_in[2];
  const float* sinb = (const float*)d_in[3];
  const float* Wq   = (const float*)d_in[4];
  const float* Wk   = (const float*)d_in[5];
  const float* Wv   = (const float*)d_in[6];
  const float* Wo   = (const float*)d_in[7];
  const float* qsc  = (const float*)d_in[8];
  const float* ksc  = (const float*)d_in[9];

  const int M = 2 * Ss;  // 4096 tokens
  // workspace (u16 elems):
  // xb    [0        .. 8388608)   x bf16 [4096][2048]; dead after QKV gemm
  // Wqkv  [8388608  .. 14680064)  W^T [3072][2048]; dead after QKV gemm
  // qbuf  [14680064 .. 23068672)  q [tok][16][128]; ctx written in-place
  // kvb   [23068672 .. 27262976)  k|v [tok][1024]
  // vTb   = alias of xb[0..2097152)   (used from vtrans onward)
  // WoT   = alias of Wqkv[0..4194304) (used from tcvt(Wo) onward)
  u16* xb   = (u16*)d_ws;
  u16* Wqkv = xb + (size_t)8388608;
  u16* qbuf = Wqkv + (size_t)6291456;
  u16* kvb  = qbuf + (size_t)8388608;
  u16* vTb  = xb;
  u16* WoT  = Wqkv;

  cvt_bf16<<<8192, 256, 0, stream>>>(x, xb, 2097152);

  tcvt<<<dim3(32, 32), 256, 0, stream>>>(Wq, Wqkv, 2048, 2048);
  tcvt<<<dim3(32, 8), 256, 0, stream>>>(Wk, Wqkv + (size_t)2048 * 2048, 512, 2048);
  tcvt<<<dim3(32, 8), 256, 0, stream>>>(Wv, Wqkv + (size_t)2560 * 2048, 512, 2048);

  // fused QKV projection: [4096][3072] split into qbuf (cols<2048) / kvb
  gemm128<0><<<dim3(32, 24), 256, 0, stream>>>(xb, Wqkv, qbuf, kvb, 2048);

  rmsrope2<<<(M * 20) / 4, 256, 0, stream>>>(qbuf, kvb, qsc, ksc, cosb, sinb);

  vtrans<<<dim3(32, 2, 8), 256, 0, stream>>>(kvb, vTb);

  attn_mfma<<<dim3(1024), 128, 0, stream>>>(qbuf, kvb, vTb, qbuf /*in-place*/);

  tcvt<<<dim3(32, 32), 256, 0, stream>>>(Wo, WoT, 2048, 2048);
  gemm128<1><<<dim3(32, 16), 256, 0, stream>>>(qbuf, WoT, d_out, nullptr, 2048);
}

// Round 8
// 319.266 us; speedup vs baseline: 1.2262x; 1.0971x over previous
//
#include <hip/hip_runtime.h>
#include <hip/hip_bf16.h>

// GQA fwd: B=2, S=2048, D_IN=2048, H=16, KV=4, Dh=128, GROUP=4, scale=1/16.
// Inputs fp32, output fp32. Intermediates bf16.
// cvt(x) + merged tcvt3(Wq|Wk|Wv) -> fused QKV m97-style single-buffered GEMM
// (3 blocks/CU) -> vectorized rmsrope(q,k) -> vtrans -> MFMA flash attn
// (R5 structure: K+V LDS-staged, ctx in-place) -> m97-style out GEMM (f32).

using u16 = unsigned short;
using u32 = unsigned int;

constexpr int Ss  = 2048;
constexpr int Hh  = 16;
constexpr int KVH = 4;

typedef __attribute__((ext_vector_type(8))) short bf16x8;
typedef __attribute__((ext_vector_type(4))) float f32x4;

__device__ inline float b2f(u16 v)  { return __uint_as_float(((u32)v) << 16); }
__device__ inline u16 f2bf(float x) {
  u32 u = __float_as_uint(x);
  return (u16)((u + 0x7fffu + ((u >> 16) & 1u)) >> 16);
}
// packed RNE f32x2 -> bf16x2 (low half = first arg)
__device__ inline u32 cvtpk(float lo, float hi) {
  u32 r;
  asm("v_cvt_pk_bf16_f32 %0, %1, %2" : "=v"(r) : "v"(lo), "v"(hi));
  return r;
}

typedef const __attribute__((address_space(1))) unsigned int gas_u32;
typedef __attribute__((address_space(3))) unsigned int las_u32;
__device__ inline void gl16(const void* g, void* l) {
  __builtin_amdgcn_global_load_lds((gas_u32*)g, (las_u32*)l, 16, 0, 0);
}

// ---------------------------------------------------------------------------
__global__ __launch_bounds__(256) void cvt_bf16(const float* __restrict__ in,
                                                u16* __restrict__ out, int n4) {
  int i = blockIdx.x * 256 + threadIdx.x;
  if (i < n4) {
    float4 f = reinterpret_cast<const float4*>(in)[i];
    ushort4 o;
    o.x = f2bf(f.x); o.y = f2bf(f.y); o.z = f2bf(f.z); o.w = f2bf(f.w);
    reinterpret_cast<ushort4*>(out)[i] = o;
  }
}

// ---------------------------------------------------------------------------
// Merged W^T convert: Wq (y<32), Wk (32<=y<40), Wv (40<=y<48) -> Wqkv buffer
// [3072][2048] bf16. 64x64 LDS tiles; paired u32 out stores.
// ---------------------------------------------------------------------------
__global__ __launch_bounds__(256) void tcvt3(const float* __restrict__ Wq,
                                             const float* __restrict__ Wk,
                                             const float* __restrict__ Wv,
                                             u16* __restrict__ out) {
  __shared__ u16 T[64][66];
  const int y = blockIdx.y, k0 = blockIdx.x * 64;
  const float* in;
  u16* o;
  int N, n0;
  if (y < 32)      { in = Wq; o = out;                         N = 2048; n0 = y * 64; }
  else if (y < 40) { in = Wk; o = out + (size_t)2048 * 2048;   N = 512;  n0 = (y - 32) * 64; }
  else             { in = Wv; o = out + (size_t)2560 * 2048;   N = 512;  n0 = (y - 40) * 64; }
  const int c = threadIdx.x & 63, rb = threadIdx.x >> 6;
#pragma unroll
  for (int p = 0; p < 16; p++) {
    int r = p * 4 + rb;
    T[c][r] = f2bf(in[(size_t)(k0 + r) * N + n0 + c]);
  }
  __syncthreads();
  const int c2 = threadIdx.x & 31, rb2 = threadIdx.x >> 5;
#pragma unroll
  for (int p = 0; p < 8; p++) {
    int nr = p * 8 + rb2;
    u32 v = *reinterpret_cast<const u32*>(&T[nr][c2 * 2]);
    *reinterpret_cast<u32*>(o + (size_t)(n0 + nr) * 2048 + k0 + c2 * 2) = v;
  }
}

// ---------------------------------------------------------------------------
// W [K][N] fp32 -> W^T [N][K] bf16 (used for Wo), 64x64 LDS tiles.
// ---------------------------------------------------------------------------
__global__ __launch_bounds__(256) void tcvt(const float* __restrict__ in,
                                            u16* __restrict__ out, int N, int K) {
  __shared__ u16 T[64][66];
  const int k0 = blockIdx.x * 64, n0 = blockIdx.y * 64;
  const int c = threadIdx.x & 63, rb = threadIdx.x >> 6;
#pragma unroll
  for (int p = 0; p < 16; p++) {
    int r = p * 4 + rb;
    T[c][r] = f2bf(in[(size_t)(k0 + r) * N + n0 + c]);
  }
  __syncthreads();
  const int c2 = threadIdx.x & 31, rb2 = threadIdx.x >> 5;
#pragma unroll
  for (int p = 0; p < 8; p++) {
    int nr = p * 8 + rb2;
    u32 v = *reinterpret_cast<const u32*>(&T[nr][c2 * 2]);
    *reinterpret_cast<u32*>(out + (size_t)(n0 + nr) * K + k0 + c2 * 2) = v;
  }
}

// ---------------------------------------------------------------------------
// v half of kv [4096 tok][1024] bf16 -> vT [(b*4+kvh)][128 d][2048 s]
// paired u32 out stores.
// ---------------------------------------------------------------------------
__global__ __launch_bounds__(256) void vtrans(const u16* __restrict__ kv,
                                              u16* __restrict__ vT) {
  __shared__ u16 T[64][66];
  const int s0 = blockIdx.x * 64, d0 = blockIdx.y * 64, z = blockIdx.z;
  const int b = z >> 2, kvh = z & 3;
  const int c = threadIdx.x & 63, rb = threadIdx.x >> 6;
#pragma unroll
  for (int p = 0; p < 16; p++) {
    int r = p * 4 + rb;
    T[c][r] = kv[(size_t)(b * Ss + s0 + r) * 1024 + 512 + kvh * 128 + d0 + c];
  }
  __syncthreads();
  const int c2 = threadIdx.x & 31, rb2 = threadIdx.x >> 5;
#pragma unroll
  for (int p = 0; p < 8; p++) {
    int dr = p * 8 + rb2;
    u32 v = *reinterpret_cast<const u32*>(&T[dr][c2 * 2]);
    *reinterpret_cast<u32*>(vT + ((size_t)z * 128 + d0 + dr) * Ss + s0 + c2 * 2) = v;
  }
}

// ---------------------------------------------------------------------------
// m97-structure 128x128-tile GEMM, BK=64, 256 threads (4 waves 2Mx2N).
// C[M x N] = A[M x K](bf16) @ Bt[N x K](bf16)^T.
// SINGLE-buffered 32KB LDS -> 3+ blocks/CU (guide m99/m100/m132: explicit
// dbuf at 64KB = 2 blocks/CU loses to m97's implicit cross-block overlap;
// 874-912 TF measured for this structure). sync -> gl16 stage -> sync
// (implicit vmcnt(0)) -> 32 MFMA. Both-sides XOR chunk swizzle (row&7).
// MODE 0: split bf16 output: cols<2048 -> C0 stride 2048 (q), cols>=2048 ->
//         C1 stride 1024 (kv). MODE 1: f32 output C0 stride 2048.
// ---------------------------------------------------------------------------
template <int MODE>
__global__ __launch_bounds__(256, 3) void gemm_bt(const u16* __restrict__ A,
                                                  const u16* __restrict__ Bt,
                                                  void* __restrict__ C0,
                                                  u16* __restrict__ C1,
                                                  int K) {
  __shared__ u16 As[128 * 64];
  __shared__ u16 Bs[128 * 64];
  const int t = threadIdx.x;
  const int wid = t >> 6, lane = t & 63;
  const int lrow = lane & 15, quad = lane >> 4;
  const int wm = wid >> 1, wn = wid & 1;  // 2x2 wave grid; per-wave 64 x 64
  const int m0 = blockIdx.x * 128, n0 = blockIdx.y * 128;
  const int sw8 = (lrow & 7) << 3;

  // staging: thread t stages LDS chunk (p*256+t), row = p*32+(t>>3),
  // col-chunk t&7 holding global col-chunk (t&7)^(row&7); read same XOR.
  const int srow = t >> 3;                      // 0..31 (+p*32)
  const int sco  = ((t & 7) ^ (srow & 7)) * 8;  // swizzled src col (u16)

  f32x4 acc[4][4];
#pragma unroll
  for (int i = 0; i < 4; i++)
#pragma unroll
    for (int j = 0; j < 4; j++) acc[i][j] = (f32x4)0.f;

  for (int k0 = 0; k0 < K; k0 += 64) {
    __syncthreads();  // all waves done reading previous tile
#pragma unroll
    for (int p = 0; p < 4; p++) {
      gl16(A + (size_t)(m0 + p * 32 + srow) * K + k0 + sco,
           (char*)As + (p * 256 + t) * 16);
      gl16(Bt + (size_t)(n0 + p * 32 + srow) * K + k0 + sco,
           (char*)Bs + (p * 256 + t) * 16);
    }
    __syncthreads();  // implicit vmcnt(0): tile staged
#pragma unroll
    for (int kc = 0; kc < 2; kc++) {
      bf16x8 af[4], bfr[4];
#pragma unroll
      for (int i = 0; i < 4; i++)
        af[i] = *reinterpret_cast<const bf16x8*>(
            &As[(wm * 64 + i * 16 + lrow) * 64 + (((kc * 4 + quad) << 3) ^ sw8)]);
#pragma unroll
      for (int j = 0; j < 4; j++)
        bfr[j] = *reinterpret_cast<const bf16x8*>(
            &Bs[(wn * 64 + j * 16 + lrow) * 64 + (((kc * 4 + quad) << 3) ^ sw8)]);
#pragma unroll
      for (int i = 0; i < 4; i++)
#pragma unroll
        for (int j = 0; j < 4; j++)
          acc[i][j] =
              __builtin_amdgcn_mfma_f32_16x16x32_bf16(af[i], bfr[j], acc[i][j], 0, 0, 0);
    }
  }

  // epilogue
  if (MODE == 0) {
    u16* C;
    int stride, coff;
    if (n0 < 2048) { C = (u16*)C0; stride = 2048; coff = n0; }
    else           { C = C1;       stride = 1024; coff = n0 - 2048; }
#pragma unroll
    for (int i = 0; i < 4; i++)
#pragma unroll
      for (int j = 0; j < 4; j++)
#pragma unroll
        for (int r = 0; r < 4; r++) {
          int row = m0 + wm * 64 + i * 16 + quad * 4 + r;
          int col = coff + wn * 64 + j * 16 + lrow;
          C[(size_t)row * stride + col] = f2bf(acc[i][j][r]);
        }
  } else {
    float* C = (float*)C0;
#pragma unroll
    for (int i = 0; i < 4; i++)
#pragma unroll
      for (int j = 0; j < 4; j++)
#pragma unroll
        for (int r = 0; r < 4; r++) {
          int row = m0 + wm * 64 + i * 16 + quad * 4 + r;
          int col = n0 + wn * 64 + j * 16 + lrow;
          C[(size_t)row * 2048 + col] = acc[i][j][r];
        }
  }
}

// ---------------------------------------------------------------------------
// Fused RMSNorm + RoPE, vectorized: one wave per 128-el vector, lane l holds
// els (2l, 2l+1) as one u32; RoPE partner via one shfl_xor(32).
// ---------------------------------------------------------------------------
__global__ __launch_bounds__(256) void rmsrope2(u16* __restrict__ qbuf,
                                                u16* __restrict__ kvb,
                                                const float* __restrict__ qsc,
                                                const float* __restrict__ ksc,
                                                const float* __restrict__ cosb,
                                                const float* __restrict__ sinb) {
  const int w = threadIdx.x >> 6, lane = threadIdx.x & 63;
  const int vi = blockIdx.x * 4 + w;
  const int tok = vi / 20, j = vi - tok * 20;
  const int s = tok & (Ss - 1);
  const bool isq = j < 16;
  u16* p = isq ? (qbuf + (size_t)tok * 2048 + j * 128)
               : (kvb + (size_t)tok * 1024 + (j - 16) * 128);
  const float* scale = isq ? qsc : ksc;
  const float mult = isq ? 0.0625f : 1.0f;

  u32* p32 = reinterpret_cast<u32*>(p);
  u32 v = p32[lane];
  float e0 = b2f((u16)(v & 0xffff)), e1 = b2f((u16)(v >> 16));
  float ss = e0 * e0 + e1 * e1;
#pragma unroll
  for (int off = 32; off > 0; off >>= 1) ss += __shfl_xor(ss, off);
  float rr = rsqrtf(ss * (1.0f / 128.0f) + 1e-6f);
  float2 sc = reinterpret_cast<const float2*>(scale)[lane];
  float x0 = e0 * rr * sc.x;
  float x1 = e1 * rr * sc.y;
  float px0 = __shfl_xor(x0, 32);
  float px1 = __shfl_xor(x1, 32);
  float2 c  = reinterpret_cast<const float2*>(cosb + s * 128)[lane];
  float2 sn = reinterpret_cast<const float2*>(sinb + s * 128)[lane];
  float sgn = (lane < 32) ? -1.0f : 1.0f;
  float o0 = (x0 * c.x + sgn * px0 * sn.x) * mult;
  float o1 = (x1 * c.y + sgn * px1 * sn.y) * mult;
  p32[lane] = cvtpk(o0, o1);
}

// ---------------------------------------------------------------------------
// MFMA flash attention (causal, GQA) -- R5 proven structure (79-86us band).
// 64-row q-tiles, 2 waves x 32 q-rows, 1024 blocks x 128 threads (4/CU).
// Single-buffered K+V gl16 staging (both-sides XOR swizzle), 2 barriers/tile;
// cross-block diversity hides the staging stall. Per-CU work uniform: CU
// group c gets blocks {c, c+256, c+512, c+768}; qt map (k=0:31-x, 1:x,
// 2:23-x, 3:8+x) sums to 66 rounds per quadruple.
// Lane-local softmax + defer-max (T13) + cvt_pk pack + transposed PV.
// ctx written IN-PLACE into qbuf (block-exclusive rows).
// ---------------------------------------------------------------------------
__global__ __launch_bounds__(128, 2) void attn_mfma(const u16* __restrict__ qb,
                                                    const u16* __restrict__ kv,
                                                    const u16* __restrict__ vT,
                                                    u16* __restrict__ ctx) {
  __shared__ u16 Ks[64 * 128];   // [key][d] linear, chunk^=(key&7)
  __shared__ u16 Vs[128 * 64];   // [d][key] linear, chunk^=(d&7)
  __shared__ u16 Ps[2][32 * 40]; // per-wave P chunk [q][key] stride 40
  const int i = blockIdx.x;
  const int kq = i >> 8, jj = i & 255, x = jj >> 5, hb = jj & 31;
  const int qtile = (kq == 0) ? 31 - x : (kq == 1) ? x : (kq == 2) ? 23 - x : 8 + x;
  const int h = hb & 15, b = hb >> 4;
  const int t = threadIdx.x, w = t >> 6, lane = t & 63;
  const int lrow = lane & 15, quad = lane >> 4;
  const int kvh = h >> 2;
  const int qw = qtile * 64 + w * 32;  // wave's first q row

  const u16* kbase = kv + (size_t)b * Ss * 1024 + kvh * 128;   // key stride 1024
  const u16* vbase = vT + (size_t)(b * KVH + kvh) * 128 * Ss;  // + d*Ss + s

  const int kr  = t >> 4;                       // K row 0..7 (+p8*8)
  const int kco = ((t & 15) ^ (kr & 7)) * 8;    // u16 offset within K row
  const int vr  = t >> 3;                       // V row 0..15 (+p8*16)
  const int vco = ((t & 7) ^ (vr & 7)) * 8;     // u16 offset within V row
  const int sw8 = (lrow & 7) << 3;              // read-side XOR (u16 units)

  // stationary Q B-frags: qf[g][c] -> Q[qw+g*16+lrow][c*32+quad*8 ..+7]
  bf16x8 qf[2][4];
#pragma unroll
  for (int g = 0; g < 2; g++)
#pragma unroll
    for (int c = 0; c < 4; c++)
      qf[g][c] = *reinterpret_cast<const bf16x8*>(
          qb + ((size_t)(b * Ss + qw + g * 16 + lrow) * Hh + h) * 128 + c * 32 + quad * 8);

  f32x4 o[2][8];  // o[g][n]: d = n*16+quad*4+r, q = qw+g*16+lrow
#pragma unroll
  for (int g = 0; g < 2; g++)
#pragma unroll
    for (int n = 0; n < 8; n++) o[g][n] = (f32x4)0.f;
  float mx[2] = {-1e30f, -1e30f}, ls[2] = {0.f, 0.f};

  const int ntile = qtile + 1;
  for (int kt = 0; kt < ntile; kt++) {
    const int kb0 = kt * 64;
    __syncthreads();  // all waves done reading previous tile's LDS
#pragma unroll
    for (int p8 = 0; p8 < 8; p8++) {
      gl16(kbase + (size_t)(kb0 + p8 * 8 + kr) * 1024 + kco,
           (char*)Ks + (p8 * 128 + t) * 16);
      gl16(vbase + (size_t)(p8 * 16 + vr) * Ss + kb0 + vco,
           (char*)Vs + (p8 * 128 + t) * 16);
    }
    __syncthreads();  // implicit vmcnt(0): staged tile ready

    // S^T[key][q]: st[g][mt], key = kb0+mt*16+quad*4+r, q = qw+g*16+lrow
    f32x4 st[2][4];
#pragma unroll
    for (int g = 0; g < 2; g++)
#pragma unroll
      for (int mt = 0; mt < 4; mt++) st[g][mt] = (f32x4)0.f;
#pragma unroll
    for (int c = 0; c < 4; c++) {
      bf16x8 kf[4];
#pragma unroll
      for (int mt = 0; mt < 4; mt++)
        kf[mt] = *reinterpret_cast<const bf16x8*>(
            &Ks[(mt * 16 + lrow) * 128 + ((((c * 4 + quad) << 3)) ^ sw8)]);
      __builtin_amdgcn_s_setprio(1);
#pragma unroll
      for (int mt = 0; mt < 4; mt++)
#pragma unroll
        for (int g = 0; g < 2; g++)
          st[g][mt] =
              __builtin_amdgcn_mfma_f32_16x16x32_bf16(kf[mt], qf[g][c], st[g][mt], 0, 0, 0);
      __builtin_amdgcn_s_setprio(0);
    }
    // causal mask (only the diagonal tile)
    if (kb0 + 63 > qw) {
#pragma unroll
      for (int g = 0; g < 2; g++) {
        int qg = qw + g * 16 + lrow;
#pragma unroll
        for (int mt = 0; mt < 4; mt++) {
          int kg = kb0 + mt * 16 + quad * 4;
#pragma unroll
          for (int rr = 0; rr < 4; rr++)
            st[g][mt][rr] = (kg + rr > qg) ? -1e30f : st[g][mt][rr];
        }
      }
    }
    // online softmax, lane-local state (q = lrow, replicated over quads)
    float tmv[2];
#pragma unroll
    for (int g = 0; g < 2; g++) {
      f32x4 m4;
#pragma unroll
      for (int rr = 0; rr < 4; rr++)
        m4[rr] = fmaxf(fmaxf(st[g][0][rr], st[g][1][rr]), fmaxf(st[g][2][rr], st[g][3][rr]));
      float tm = fmaxf(fmaxf(m4[0], m4[1]), fmaxf(m4[2], m4[3]));
      tm = fmaxf(tm, __shfl_xor(tm, 16));
      tm = fmaxf(tm, __shfl_xor(tm, 32));
      tmv[g] = tm;
    }
    // defer-max (T13): rescale only if some row grew its max by >8.
    if (__any((tmv[0] > mx[0] + 8.0f) || (tmv[1] > mx[1] + 8.0f))) {
#pragma unroll
      for (int g = 0; g < 2; g++) {
        float mn = fmaxf(mx[g], tmv[g]);
        float a = __expf(mx[g] - mn);
        mx[g] = mn;
        ls[g] *= a;
#pragma unroll
        for (int n = 0; n < 8; n++) o[g][n] *= a;
      }
    }
#pragma unroll
    for (int g = 0; g < 2; g++) {
      float tsum = 0.f;
#pragma unroll
      for (int mt = 0; mt < 4; mt++)
#pragma unroll
        for (int rr = 0; rr < 4; rr++) {
          float pv = __expf(st[g][mt][rr] - mx[g]);
          st[g][mt][rr] = pv;
          tsum += pv;
        }
      tsum += __shfl_xor(tsum, 16);
      tsum += __shfl_xor(tsum, 32);
      ls[g] += tsum;
    }
    // PV in 2 key-chunks of 32: pack P (cvt_pk) -> per-wave LDS -> B-frag
    // P^T[k][q]; per-wave in-order DS ops make the chunk reuse safe.
#pragma unroll
    for (int c2 = 0; c2 < 2; c2++) {
#pragma unroll
      for (int g = 0; g < 2; g++)
#pragma unroll
        for (int mh = 0; mh < 2; mh++) {
          const f32x4 sv = st[g][c2 * 2 + mh];
          uint2 pk;
          pk.x = cvtpk(sv[0], sv[1]);
          pk.y = cvtpk(sv[2], sv[3]);
          *reinterpret_cast<uint2*>(
              &Ps[w][(g * 16 + lrow) * 40 + mh * 16 + quad * 4]) = pk;
        }
      bf16x8 pfr[2];
#pragma unroll
      for (int g = 0; g < 2; g++)
        pfr[g] = *reinterpret_cast<const bf16x8*>(
            &Ps[w][(g * 16 + lrow) * 40 + quad * 8]);
      __builtin_amdgcn_s_setprio(1);
#pragma unroll
      for (int n = 0; n < 8; n++) {
        bf16x8 vf = *reinterpret_cast<const bf16x8*>(
            &Vs[(n * 16 + lrow) * 64 + ((((c2 * 4 + quad) << 3)) ^ sw8)]);
#pragma unroll
        for (int g = 0; g < 2; g++)
          o[g][n] = __builtin_amdgcn_mfma_f32_16x16x32_bf16(vf, pfr[g], o[g][n], 0, 0, 0);
      }
      __builtin_amdgcn_s_setprio(0);
    }
  }

  // epilogue: divide by l (lane-local), packed bf16 store
#pragma unroll
  for (int g = 0; g < 2; g++) {
    float linv = 1.0f / ls[g];
    u16* obase = ctx + ((size_t)(b * Ss + qw + g * 16 + lrow) * Hh + h) * 128 + quad * 4;
#pragma unroll
    for (int n = 0; n < 8; n++) {
      uint2 pk;
      pk.x = cvtpk(o[g][n][0] * linv, o[g][n][1] * linv);
      pk.y = cvtpk(o[g][n][2] * linv, o[g][n][3] * linv);
      *reinterpret_cast<uint2*>(obase + n * 16) = pk;
    }
  }
}

// ---------------------------------------------------------------------------
extern "C" void kernel_launch(void* const* d_in, const int* in_sizes, int n_in,
                              void* d_out, int out_size, void* d_ws, size_t ws_size,
                              hipStream_t stream) {
  const float* x    = (const float*)d_in[0];
  // d_in[1] = mask (unused; causal handled analytically)
  const float* cosb = (const float*)d_in[2];
  const float* sinb = (const float*)d_in[3];
  const float* Wq   = (const float*)d_in[4];
  const float* Wk   = (const float*)d_in[5];
  const float* Wv   = (const float*)d_in[6];
  const float* Wo   = (const float*)d_in[7];
  const float* qsc  = (const float*)d_in[8];
  const float* ksc  = (const float*)d_in[9];

  const int M = 2 * Ss;  // 4096 tokens
  // workspace (u16 elems):
  // xb    [0        .. 8388608)   x bf16 [4096][2048]; dead after QKV gemm
  // Wqkv  [8388608  .. 14680064)  W^T [3072][2048]; dead after QKV gemm
  // qbuf  [14680064 .. 23068672)  q [tok][16][128]; ctx written in-place
  // kvb   [23068672 .. 27262976)  k|v [tok][1024]
  // vTb   = alias of xb[0..2097152)   (used from vtrans onward)
  // WoT   = alias of Wqkv[0..4194304) (used from tcvt(Wo) onward)
  u16* xb   = (u16*)d_ws;
  u16* Wqkv = xb + (size_t)8388608;
  u16* qbuf = Wqkv + (size_t)6291456;
  u16* kvb  = qbuf + (size_t)8388608;
  u16* vTb  = xb;
  u16* WoT  = Wqkv;

  cvt_bf16<<<8192, 256, 0, stream>>>(x, xb, 2097152);

  tcvt3<<<dim3(32, 48), 256, 0, stream>>>(Wq, Wk, Wv, Wqkv);

  // fused QKV projection: [4096][3072] split into qbuf (cols<2048) / kvb
  gemm_bt<0><<<dim3(32, 24), 256, 0, stream>>>(xb, Wqkv, qbuf, kvb, 2048);

  rmsrope2<<<(M * 20) / 4, 256, 0, stream>>>(qbuf, kvb, qsc, ksc, cosb, sinb);

  vtrans<<<dim3(32, 2, 8), 256, 0, stream>>>(kvb, vTb);

  attn_mfma<<<dim3(1024), 128, 0, stream>>>(qbuf, kvb, vTb, qbuf /*in-place*/);

  tcvt<<<dim3(32, 32), 256, 0, stream>>>(Wo, WoT, 2048, 2048);
  gemm_bt<1><<<dim3(32, 16), 256, 0, stream>>>(qbuf, WoT, d_out, nullptr, 2048);
}